// Round 14
// baseline (346.268 us; speedup 1.0000x reference)
//
#include <hip/hip_runtime.h>
#include <hip/hip_bf16.h>
#include <cstdint>
#include <cstddef>

// Masked causal dense attention, B=8, Tq=Tv=2048, D=512, key==value.
// R14 = R12's proven no-spill datapath (16x16 full-K QK, d-split pairs, in-reg
// P-shuffle) restructured for 2 blocks/CU: 4-wave 256-thr blocks, LDS 65.8KB
// (single-buffered sV+sVT+masks), counted-vmcnt 4-barrier pipeline (every
// vmcnt has a compute-phase of slack), R13-verified full (v&7) sV swizzle.
// Schedule: 64 groups (2x16-row q-tiles, uniform causal bound g),
// NS(g)=ceil((g+1)/11), 219 slots/batch, grid 1752, LPT order.

#define TQ   2048
#define TV   2048
#define DIM  512
#define NB   8
#define NROW (NB * TQ)
#define NSLOT 219   // sum over g=0..63 of NS(g)

typedef _Float16 f16x8 __attribute__((ext_vector_type(8)));
typedef _Float16 f16x4 __attribute__((ext_vector_type(4)));
typedef float    f32x4 __attribute__((ext_vector_type(4)));
typedef int      i32x4 __attribute__((ext_vector_type(4)));

__device__ __forceinline__ int sched_ns(int g) { return (g + 11) / 11; }

// ---- mask dtype runtime detection (bool may arrive as u8 / i32 / i64 / f32) ----
__device__ __forceinline__ int mask_fmt(const void* qm) {
    const unsigned* p = (const unsigned*)qm;
    unsigned w0 = p[0];
    if (w0 & 0xFF00u) return 0;                  // u8
    unsigned w1 = p[1];
    if (w0 == 1u) return (w1 != 0u) ? 1 : 2;     // i32 vs i64
    return 3;                                     // f32
}
__device__ __forceinline__ bool mask_bit(const void* m, int fmt, size_t i) {
    if (fmt == 0) return ((const unsigned char*)m)[i] != 0;
    if (fmt == 1) return ((const int*)m)[i] != 0;
    if (fmt == 2) return ((const unsigned*)m)[2 * i] != 0;
    return ((const float*)m)[i] != 0.0f;
}

// global -> LDS DMA, 16B per lane; LDS dest = uniform base + lane*16 (linear)
__device__ __forceinline__ void gload_lds16(const void* g, void* l) {
    __builtin_amdgcn_global_load_lds(
        (const __attribute__((address_space(1))) unsigned int*)g,
        (__attribute__((address_space(3))) unsigned int*)l, 16, 0, 0);
}

__global__ void cvt_f16_kernel(const float* __restrict__ in, _Float16* __restrict__ out, int n8) {
    int i = blockIdx.x * blockDim.x + threadIdx.x;
    if (i >= n8) return;
    f32x4 x0 = *(const f32x4*)(in + (size_t)i * 8);
    f32x4 x1 = *(const f32x4*)(in + (size_t)i * 8 + 4);
    f16x8 o;
#pragma unroll
    for (int j = 0; j < 4; ++j) { o[j] = (_Float16)x0[j]; o[4 + j] = (_Float16)x1[j]; }
    *(f16x8*)(out + (size_t)i * 8) = o;
}

// ---- V f32 -> wv f16 row-major + wvt f16 transposed [b][d][v] (64x64 LDS tiles) ----
__global__ __launch_bounds__(256)
void prep_v_kernel(const float* __restrict__ vf, _Float16* __restrict__ wv,
                   _Float16* __restrict__ wvt) {
    __shared__ float sT[64][65];
    int z   = blockIdx.x;
    int b   = z & 7;
    int tv0 = ((z >> 3) & 31) * 64;
    int d0  = (z >> 8) * 64;
    int tid = threadIdx.x;
    int vl  = tid >> 4;
    int dq  = (tid & 15) * 4;
#pragma unroll
    for (int i = 0; i < 4; ++i) {
        int v = vl + i * 16;
        f32x4 x = *(const f32x4*)(vf + ((size_t)b * TV + tv0 + v) * DIM + d0 + dq);
        f16x4 h;
#pragma unroll
        for (int j = 0; j < 4; ++j) { h[j] = (_Float16)x[j]; sT[v][dq + j] = x[j]; }
        *(f16x4*)(wv + ((size_t)b * TV + tv0 + v) * DIM + d0 + dq) = h;
    }
    __syncthreads();
    int dl = tid >> 4;           // 0..15
    int vq = (tid & 15) * 4;     // 0..60
#pragma unroll
    for (int i = 0; i < 4; ++i) {
        int dloc = dl + i * 16;
        f16x4 h;
#pragma unroll
        for (int j = 0; j < 4; ++j) h[j] = (_Float16)sT[vq + j][dloc];
        *(f16x4*)(wvt + ((size_t)b * DIM + d0 + dloc) * TV + tv0 + vq) = h;
    }
}

__global__ __launch_bounds__(256)
__attribute__((amdgpu_waves_per_eu(2, 2)))
void attn_kernel(const _Float16* __restrict__ wq, const _Float16* __restrict__ wv,
                 const _Float16* __restrict__ wvt,
                 const void* __restrict__ qmask, const void* __restrict__ vmask,
                 _Float16* __restrict__ pacc, float* __restrict__ pml) {
    // 65792 B LDS -> 2 blocks/CU (8 waves/CU = 2/SIMD, matches waves_per_eu(2,2)).
    __shared__ __align__(16) _Float16 sV[32 * 512];  // [32 v][512 k]; chunk c at c^(v&7)
    __shared__ __align__(16) char     sVT[512 * 64]; // [512 d][32 v]; chunk c at c^(d&3)
    __shared__ unsigned sMW[64];                     // per-KV-tile v_mask words

    const int tid  = threadIdx.x;
    const int lane = tid & 63;
    const int w    = tid >> 6;        // wave 0..3
    const int q16  = lane & 15;
    const int grp  = lane >> 4;       // 0..3

    const int bid  = blockIdx.x;
    const int b    = bid & 7;                    // batch -> XCD L2 locality
    const int slot = (NSLOT - 1) - (bid >> 3);   // LPT: longest (large g) first

    // slot -> (g, s)
    int g = 0, s = 0;
    {
        int base = 0;
#pragma unroll
        for (int j = 0; j < 64; ++j) {
            int n = sched_ns(j);
            if (slot >= base && slot < base + n) { g = j; s = slot - base; }
            base += n;
        }
    }
    const int NSg = sched_ns(g);

    const int pairId = w >> 1;            // q-tile within block (rows g*32 + pairId*16 ..)
    const int dhalf  = w & 1;             // PV d-half owned by this wave
    const int qrow   = g * 32 + pairId * 16 + q16;
    const size_t qrowG = (size_t)b * TQ + qrow;
    // causal bound: rows g*32..g*32+31 -> KV tiles t <= g, uniform per block

    const int fmt = mask_fmt(qmask);

    // q activity: one ballot over the block's 32 rows (lanes 32..63 duplicate)
    unsigned long long qbal = __ballot(mask_bit(qmask, fmt, (size_t)b * TQ + g * 32 + (lane & 31)));
    const bool act0 = (qbal & 0xFFFFull) != 0ull;
    const bool act1 = (qbal & 0xFFFF0000ull) != 0ull;
    const bool waveActive = pairId ? act1 : act0;
    const int  bmaxb = (act0 || act1) ? g : -1;

    // v_mask table (wave 0 fills via ballots; visible after prologue barrier)
    if (w == 0) {
#pragma unroll
        for (int c = 0; c < 32; ++c) {
            unsigned long long bal = __ballot(mask_bit(vmask, fmt, (size_t)b * TV + c * 64 + lane));
            if (lane == 0) {
                sMW[2 * c]     = (unsigned)(bal & 0xFFFFFFFFull);
                sMW[2 * c + 1] = (unsigned)(bal >> 32);
            }
        }
    }

    // ---- Q B-frags: lane holds Q[qrow][kc*32 + grp*8 + j] (full K; dup per d-pair) ----
    f16x8 qreg[16];
    if (waveActive) {
#pragma unroll
        for (int kc = 0; kc < 16; ++kc)
            qreg[kc] = *(const f16x8*)(wq + qrowG * DIM + kc * 32 + grp * 8);
    }

    // ---- staging: 8 DMA loads per wave per buffer ----
    auto stage_sV = [&](int tt) {      // rows w*8..w*8+7; src pre-swizzled chunk^(v&7)
#pragma unroll
        for (int k = 0; k < 8; ++k) {
            int vr = w * 8 + k;
            const _Float16* src = wv + ((size_t)b * TV + tt * 32 + vr) * DIM
                                     + ((lane ^ (vr & 7)) << 3);
            gload_lds16(src, (char*)sV + vr * 1024);
        }
    };
    auto stage_sVT = [&](int tt) {     // 512 rows x 4 chunks; src pre-swizzled chunk^(d&3)
#pragma unroll
        for (int k = 0; k < 8; ++k) {
            int slot2 = w * 512 + k * 64 + lane;   // 0..2047
            int dloc  = slot2 >> 2;
            int cl    = slot2 & 3;
            const _Float16* src = wvt + ((size_t)b * DIM + dloc) * TV + tt * 32
                                      + ((cl ^ (dloc & 3)) << 3);
            gload_lds16(src, sVT + w * 8192 + k * 1024);
        }
    };

    f32x4 acc[16];   // out^T[dhalf*256 + c*16 + grp*4 + j][q16]
#pragma unroll
    for (int c = 0; c < 16; ++c) acc[c] = (f32x4){0.f, 0.f, 0.f, 0.f};
    float m_run = -3.0e38f, l_run = 0.0f;

    const int sw = q16 & 7;   // sV read swizzle (full v&7 — R13-verified fix)

    if (bmaxb >= s) {
        stage_sV(s);
        stage_sVT(s);
        asm volatile("s_waitcnt vmcnt(0) lgkmcnt(0)" ::: "memory");  // tiles + sMW ready
        __builtin_amdgcn_s_barrier();

        for (int t = s; t <= bmaxb; t += NSg) {
            const int vb = t * 32;
            const unsigned mw = sMW[t];            // uniform LDS broadcast, no VMEM
            if (mw == 0u) break;                   // monotone length mask; uniform
            const bool act = waveActive;           // bound==g>=t always
            int tn = t + NSg; if (tn > bmaxb) tn = bmaxb;

            // === QK: S^T = V x Q^T (full K=512, 4 chains; dup across d-pair) ===
            f32x4 s0a = (f32x4){0.f,0.f,0.f,0.f}, s0b = s0a, s1a = s0a, s1b = s0a;
            if (act) {
                __builtin_amdgcn_s_setprio(1);
#pragma unroll
                for (int kc = 0; kc < 16; kc += 2) {
                    int c0 = ((kc * 4 + grp) ^ sw) << 4;
                    int c1 = (((kc + 1) * 4 + grp) ^ sw) << 4;
                    f16x8 a00 = *(const f16x8*)((const char*)sV + q16 * 1024 + c0);
                    s0a = __builtin_amdgcn_mfma_f32_16x16x32_f16(a00, qreg[kc], s0a, 0, 0, 0);
                    f16x8 a10 = *(const f16x8*)((const char*)sV + (16 + q16) * 1024 + c0);
                    s1a = __builtin_amdgcn_mfma_f32_16x16x32_f16(a10, qreg[kc], s1a, 0, 0, 0);
                    f16x8 a01 = *(const f16x8*)((const char*)sV + q16 * 1024 + c1);
                    s0b = __builtin_amdgcn_mfma_f32_16x16x32_f16(a01, qreg[kc + 1], s0b, 0, 0, 0);
                    f16x8 a11 = *(const f16x8*)((const char*)sV + (16 + q16) * 1024 + c1);
                    s1b = __builtin_amdgcn_mfma_f32_16x16x32_f16(a11, qreg[kc + 1], s1b, 0, 0, 0);
                }
                __builtin_amdgcn_s_setprio(0);
            }
            __builtin_amdgcn_s_barrier();          // B1: sV(t) reads done block-wide
            stage_sV(tn);                          // +8 (overwrite sV; lands before B4)

            f16x8 pf;
            if (act) {
                f32x4 s0 = s0a + s0b, s1 = s1a + s1b;
                float p[8];
                float tm = -3.0e38f;
#pragma unroll
                for (int i = 0; i < 8; ++i) {
                    int vloc = ((i < 4) ? 0 : 16) + grp * 4 + (i & 3);
                    float x = (i < 4) ? s0[i] : s1[i - 4];
                    bool valid = ((vb + vloc) <= qrow) && ((mw >> vloc) & 1u);
                    x = valid ? x : (x - 1e9f);
                    p[i] = x;
                    tm = fmaxf(tm, x);
                }
                tm = fmaxf(tm, __shfl_xor(tm, 16, 64));
                tm = fmaxf(tm, __shfl_xor(tm, 32, 64));
                if (!__all(tm <= m_run + 8.0f)) {          // defer-max (T13)
                    float mn = fmaxf(m_run, tm);
                    float rr = __expf(m_run - mn);
                    l_run *= rr;
#pragma unroll
                    for (int c = 0; c < 16; ++c) acc[c] *= rr;
                    m_run = mn;
                }
                float ps = 0.0f;
#pragma unroll
                for (int i = 0; i < 8; ++i) { p[i] = __expf(p[i] - m_run); ps += p[i]; }
                ps += __shfl_xor(ps, 16, 64);
                ps += __shfl_xor(ps, 32, 64);
                l_run += ps;

                // P B-frag in-register (verified R8/R9/R12): shuffle both pairs, select at dest
                int pk0 = __builtin_bit_cast(int, __builtin_amdgcn_cvt_pkrtz(p[0], p[1]));
                int pk1 = __builtin_bit_cast(int, __builtin_amdgcn_cvt_pkrtz(p[2], p[3]));
                int pk2 = __builtin_bit_cast(int, __builtin_amdgcn_cvt_pkrtz(p[4], p[5]));
                int pk3 = __builtin_bit_cast(int, __builtin_amdgcn_cvt_pkrtz(p[6], p[7]));
                int lo = q16 + ((grp & 1) << 5);
                int hi = lo + 16;
                int a0 = __shfl(pk0, lo, 64);
                int a1 = __shfl(pk1, lo, 64);
                int a2 = __shfl(pk0, hi, 64);
                int a3 = __shfl(pk1, hi, 64);
                int c0s = __shfl(pk2, lo, 64);
                int c1s = __shfl(pk3, lo, 64);
                int c2s = __shfl(pk2, hi, 64);
                int c3s = __shfl(pk3, hi, 64);
                bool hb = (grp & 2) != 0;
                i32x4 f;
                f[0] = hb ? c0s : a0;
                f[1] = hb ? c1s : a1;
                f[2] = hb ? c2s : a2;
                f[3] = hb ? c3s : a3;
                pf = __builtin_bit_cast(f16x8, f);
            }
            // sVT(t) was staged one full iteration ago -> plenty of slack
            asm volatile("s_waitcnt vmcnt(8)" ::: "memory");   // sVT(t) landed (own 8)
            __builtin_amdgcn_s_barrier();                      // B2: sVT(t) ready block-wide

            // === PV: out^T[d][q16] += VT x P^T over this wave's 256-d half ===
            if (act) {
                __builtin_amdgcn_s_setprio(1);
#pragma unroll
                for (int c = 0; c < 16; ++c) {
                    int d = dhalf * 256 + c * 16 + q16;
                    f16x8 a = *(const f16x8*)(sVT + d * 64 + ((grp ^ (d & 3)) << 4));
                    acc[c] = __builtin_amdgcn_mfma_f32_16x16x32_f16(a, pf, acc[c], 0, 0, 0);
                }
                __builtin_amdgcn_s_setprio(0);
            }
            __builtin_amdgcn_s_barrier();              // B3: sVT(t) reads done
            stage_sVT(tn);                             // +8 (overwrite sVT)
            asm volatile("s_waitcnt vmcnt(8)" ::: "memory");  // sV(tn) landed (slack: softmax+PV)
            __builtin_amdgcn_s_barrier();              // B4: sV(tn) ready block-wide
        }
    }
    asm volatile("s_waitcnt vmcnt(0) lgkmcnt(0)" ::: "memory");

    // ---- epilogue: normalized f16 partials + (m,l) ----
    float inv = (l_run > 0.f) ? (1.0f / l_run) : 0.0f;
    int rowInB = pairId * 16 + q16;
    _Float16* pb = pacc + (((size_t)(b * NSLOT + slot) * 32) + rowInB) * DIM;
#pragma unroll
    for (int c = 0; c < 16; ++c) {
        f16x4 hh;
#pragma unroll
        for (int j = 0; j < 4; ++j) hh[j] = (_Float16)(acc[c][j] * inv);
        *(f16x4*)(pb + dhalf * 256 + c * 16 + grp * 4) = hh;
    }
    if (dhalf == 0 && grp == 0) {
        size_t mi = (((size_t)(b * NSLOT + slot) * 32) + rowInB) * 2;
        pml[mi]     = m_run;
        pml[mi + 1] = l_run;
    }
}

__global__ __launch_bounds__(256)
void combine_kernel(const _Float16* __restrict__ pacc, const float* __restrict__ pml,
                    const void* __restrict__ qmask, float* __restrict__ out) {
    int gid = blockIdx.x * 256 + threadIdx.x;
    int row = gid >> 7;
    int c   = (gid & 127) * 4;
    if (row >= NROW) return;
    int b      = row >> 11;
    int local  = row & 2047;
    int g      = local >> 5;          // 32 rows per group
    int rowInG = local & 31;
    int ns     = sched_ns(g);
    int st     = 0;
    for (int j = 0; j < 64; ++j) if (j < g) st += sched_ns(j);

    float m = -3.0e38f;
    for (int s2 = 0; s2 < ns; ++s2) {
        size_t idx = ((size_t)(b * NSLOT + st + s2) * 32) + rowInG;
        float l2 = pml[idx * 2 + 1];
        if (l2 > 0.f) m = fmaxf(m, pml[idx * 2]);
    }
    float L = 0.f;
    f32x4 o = (f32x4){0.f, 0.f, 0.f, 0.f};
    for (int s2 = 0; s2 < ns; ++s2) {
        size_t idx = ((size_t)(b * NSLOT + st + s2) * 32) + rowInG;
        float l2 = pml[idx * 2 + 1];
        if (l2 > 0.f) {
            float wgt = __expf(pml[idx * 2] - m) * l2;
            L += wgt;
            f16x4 hh = *(const f16x4*)(pacc + idx * DIM + c);
#pragma unroll
            for (int j = 0; j < 4; ++j) o[j] += wgt * (float)hh[j];
        }
    }
    int fmt = mask_fmt(qmask);
    bool qb = mask_bit(qmask, fmt, (size_t)row);
    float invL = (L > 0.f && qb) ? (1.0f / L) : 0.f;
    o *= invL;
    *(f32x4*)(out + (size_t)row * DIM + c) = o;
}

extern "C" void kernel_launch(void* const* d_in, const int* in_sizes, int n_in,
                              void* d_out, int out_size, void* d_ws, size_t ws_size,
                              hipStream_t stream) {
    const float* q = (const float*)d_in[0];
    const float* v = (const float*)d_in[1];
    const void* qm = d_in[2];
    const void* vm = d_in[3];
    float* out = (float*)d_out;

    const size_t nElem = (size_t)NB * TQ * DIM;                    // 8,388,608
    const size_t wqB   = nElem * sizeof(_Float16);                 // 16.78 MB
    const size_t wvB   = wqB, wvtB = wqB;
    const size_t paccB = (size_t)NB * NSLOT * 32 * DIM * sizeof(_Float16);  // 57.4 MB
    const size_t pmlB  = (size_t)NB * NSLOT * 32 * 2 * sizeof(float);       // 0.45 MB

    if (ws_size < wqB + wvB + wvtB + paccB + pmlB) {   // ~108 MB; R7 proved >=116 available
        (void)hipMemsetAsync(d_out, 0, (size_t)out_size * sizeof(float), stream);
        return;
    }
    _Float16* wq   = (_Float16*)d_ws;
    _Float16* wv   = (_Float16*)((char*)d_ws + wqB);
    _Float16* wvt  = (_Float16*)((char*)d_ws + wqB + wvB);
    _Float16* pacc = (_Float16*)((char*)d_ws + wqB + wvB + wvtB);
    float*    pml  = (float*)((char*)d_ws + wqB + wvB + wvtB + paccB);

    int n8 = (int)(nElem / 8);
    cvt_f16_kernel<<<dim3(n8 / 256), dim3(256), 0, stream>>>(q, wq, n8);
    prep_v_kernel<<<dim3(2048), dim3(256), 0, stream>>>(v, wv, wvt);
    attn_kernel<<<dim3(NB * NSLOT), dim3(256), 0, stream>>>(wq, wv, wvt, qm, vm, pacc, pml);
    combine_kernel<<<dim3(NROW * 128 / 256), dim3(256), 0, stream>>>(pacc, pml, qm, out);
}

// Round 15
// 177.846 us; speedup vs baseline: 1.9470x; 1.9470x over previous
//
#include <hip/hip_runtime.h>
#include <hip/hip_bf16.h>
#include <cstdint>
#include <cstddef>

// Masked causal dense attention, B=8, Tq=Tv=2048, D=512, key==value.
// R15 = R12 (champion, 157us attn, 116 VGPR no-spill) with ONE change:
// sVT rows padded 64B -> 80B (R13-verified staging). R9/R12/R14 all showed
// the IDENTICAL 9,147,424 bank-conflict count — traced to sVT's 64B row
// stride (rows d, d+2 alias at 128B -> ~8-way conflict on PV b128 reads).
// 80B rows: slot = (5d + grp) mod 8, 5 coprime 8 -> provably even.
// Everything else (registers, schedule, barriers, swizzles) is R12 verbatim.

#define TQ   2048
#define TV   2048
#define DIM  512
#define NB   8
#define NROW (NB * TQ)
#define NSLOT 63

typedef _Float16 f16x8 __attribute__((ext_vector_type(8)));
typedef _Float16 f16x4 __attribute__((ext_vector_type(4)));
typedef float    f32x4 __attribute__((ext_vector_type(4)));
typedef int      i32x4 __attribute__((ext_vector_type(4)));

__device__ __forceinline__ int sched_ns(int g) { return (g + 11) / 11; }
__device__ __forceinline__ int sched_start(int g) {
    return (g < 11) ? g : ((g < 22) ? (2 * g - 11) : (3 * g - 33));
}

// ---- mask dtype runtime detection (bool may arrive as u8 / i32 / i64 / f32) ----
__device__ __forceinline__ int mask_fmt(const void* qm) {
    const unsigned* p = (const unsigned*)qm;
    unsigned w0 = p[0];
    if (w0 & 0xFF00u) return 0;                  // u8
    unsigned w1 = p[1];
    if (w0 == 1u) return (w1 != 0u) ? 1 : 2;     // i32 vs i64
    return 3;                                     // f32
}
__device__ __forceinline__ bool mask_bit(const void* m, int fmt, size_t i) {
    if (fmt == 0) return ((const unsigned char*)m)[i] != 0;
    if (fmt == 1) return ((const int*)m)[i] != 0;
    if (fmt == 2) return ((const unsigned*)m)[2 * i] != 0;
    return ((const float*)m)[i] != 0.0f;
}

// global -> LDS DMA, 16B per lane; LDS dest = uniform base + lane*16 (linear)
__device__ __forceinline__ void gload_lds16(const void* g, void* l) {
    __builtin_amdgcn_global_load_lds(
        (const __attribute__((address_space(1))) unsigned int*)g,
        (__attribute__((address_space(3))) unsigned int*)l, 16, 0, 0);
}

__global__ void cvt_f16_kernel(const float* __restrict__ in, _Float16* __restrict__ out, int n8) {
    int i = blockIdx.x * blockDim.x + threadIdx.x;
    if (i >= n8) return;
    f32x4 x0 = *(const f32x4*)(in + (size_t)i * 8);
    f32x4 x1 = *(const f32x4*)(in + (size_t)i * 8 + 4);
    f16x8 o;
#pragma unroll
    for (int j = 0; j < 4; ++j) { o[j] = (_Float16)x0[j]; o[4 + j] = (_Float16)x1[j]; }
    *(f16x8*)(out + (size_t)i * 8) = o;
}

// ---- V f32 -> wv f16 row-major + wvt f16 transposed [b][d][v] (64x64 LDS tiles) ----
__global__ __launch_bounds__(256)
void prep_v_kernel(const float* __restrict__ vf, _Float16* __restrict__ wv,
                   _Float16* __restrict__ wvt) {
    __shared__ float sT[64][65];
    int z   = blockIdx.x;
    int b   = z & 7;
    int tv0 = ((z >> 3) & 31) * 64;
    int d0  = (z >> 8) * 64;
    int tid = threadIdx.x;
    int vl  = tid >> 4;
    int dq  = (tid & 15) * 4;
#pragma unroll
    for (int i = 0; i < 4; ++i) {
        int v = vl + i * 16;
        f32x4 x = *(const f32x4*)(vf + ((size_t)b * TV + tv0 + v) * DIM + d0 + dq);
        f16x4 h;
#pragma unroll
        for (int j = 0; j < 4; ++j) { h[j] = (_Float16)x[j]; sT[v][dq + j] = x[j]; }
        *(f16x4*)(wv + ((size_t)b * TV + tv0 + v) * DIM + d0 + dq) = h;
    }
    __syncthreads();
    int dl = tid >> 4;           // 0..15
    int vq = (tid & 15) * 4;     // 0..60
#pragma unroll
    for (int i = 0; i < 4; ++i) {
        int dloc = dl + i * 16;
        f16x4 h;
#pragma unroll
        for (int j = 0; j < 4; ++j) h[j] = (_Float16)sT[vq + j][dloc];
        *(f16x4*)(wvt + ((size_t)b * DIM + d0 + dloc) * TV + tv0 + vq) = h;
    }
}

__global__ __launch_bounds__(512)
__attribute__((amdgpu_waves_per_eu(2, 2)))
void attn_kernel(const _Float16* __restrict__ wq, const _Float16* __restrict__ wv,
                 const _Float16* __restrict__ wvt,
                 const void* __restrict__ qmask, const void* __restrict__ vmask,
                 _Float16* __restrict__ pacc, float* __restrict__ pml) {
    // 144.25 KB LDS -> 1 block/CU (8 waves = 2/SIMD, matching waves_per_eu(2,2)).
    __shared__ __align__(16) _Float16 sV[2][32 * 512];  // [32 v][512 k]; chunk c at c^((v&7)<<2)
    __shared__ __align__(16) char     sVT[2][512 * 80]; // [512 d] x 80B rows (64B data + 16B pad)
    __shared__ unsigned sMW[64];                        // per-KV-tile v_mask words

    const int tid  = threadIdx.x;
    const int lane = tid & 63;
    const int w    = tid >> 6;        // wave 0..7
    const int q16  = lane & 15;
    const int grp  = lane >> 4;       // 0..3

    const int bid  = blockIdx.x;
    const int b    = bid & 7;                    // batch -> XCD L2 locality
    const int slot = (NSLOT - 1) - (bid >> 3);   // LPT: longest (large g) first

    // slot -> (g, s)
    int g = 0, s = 0;
#pragma unroll
    for (int j = 0; j < 32; ++j) {
        int st = sched_start(j);
        if (slot >= st && slot < st + sched_ns(j)) { g = j; s = slot - st; }
    }
    const int NSg = sched_ns(g);

    const int pairId = w >> 1;            // 0..3: q-tile within group
    const int dhalf  = w & 1;             // PV d-half owned by this wave
    const int qtile  = 4 * g + pairId;
    const int qrow   = qtile * 16 + q16;
    const size_t qrowG = (size_t)b * TQ + qrow;
    const int bound = qtile >> 1;         // causal KV-tile bound (32-tiles)

    const int fmt = mask_fmt(qmask);

    // q activity: one ballot over the block's 64 rows
    unsigned long long qbal = __ballot(mask_bit(qmask, fmt, (size_t)b * TQ + g * 64 + lane));
    const bool waveActive = ((qbal >> (16 * pairId)) & 0xFFFFull) != 0ull;
    int bmaxb = -1;
#pragma unroll
    for (int ti = 0; ti < 4; ++ti)
        if ((qbal >> (16 * ti)) & 0xFFFFull) bmaxb = max(bmaxb, (4 * g + ti) >> 1);

    // v_mask table (wave 0 fills via ballots)
    if (w == 0) {
#pragma unroll
        for (int c = 0; c < 32; ++c) {
            unsigned long long bal = __ballot(mask_bit(vmask, fmt, (size_t)b * TV + c * 64 + lane));
            if (lane == 0) {
                sMW[2 * c]     = (unsigned)(bal & 0xFFFFFFFFull);
                sMW[2 * c + 1] = (unsigned)(bal >> 32);
            }
        }
    }

    // ---- Q B-frags: lane holds Q[qrow][kc*32 + grp*8 + j] (full K; dup per d-pair) ----
    f16x8 qreg[16];
    if (waveActive) {
#pragma unroll
        for (int kc = 0; kc < 16; ++kc)
            qreg[kc] = *(const f16x8*)(wq + qrowG * DIM + kc * 32 + grp * 8);
    }

    // ---- staging: 4 sV + 5 sVT DMA loads per wave into buffer `buf` ----
    auto stage = [&](int buf, int tt) {
#pragma unroll
        for (int k = 0; k < 4; ++k) {
            int vr = w * 4 + k;
            const _Float16* src = wv + ((size_t)b * TV + tt * 32 + vr) * DIM
                                     + ((lane ^ ((vr & 7) << 2)) << 3);
            gload_lds16(src, (char*)&sV[buf][0] + vr * 1024);
        }
        // sVT: wave's 64 d-rows x 80B = 5120B = 5 loads; row d at byte d*80,
        // chunks c=0..3 at 16c (dummy 5th slot refetches c=0 into the pad).
#pragma unroll
        for (int k = 0; k < 5; ++k) {
            int slot2 = k * 64 + lane;       // 0..319
            int dloc  = slot2 / 5;           // 0..63 within wave's rows
            int c     = slot2 - dloc * 5;
            int cs    = (c >= 4) ? 0 : c;
            const _Float16* src = wvt + ((size_t)b * DIM + w * 64 + dloc) * TV + tt * 32 + cs * 8;
            gload_lds16(src, &sVT[buf][0] + w * 5120 + k * 1024);
        }
    };

    f32x4 acc[16];   // out^T[dhalf*256 + c*16 + grp*4 + j][q16]
#pragma unroll
    for (int c = 0; c < 16; ++c) acc[c] = (f32x4){0.f, 0.f, 0.f, 0.f};
    float m_run = -3.0e38f, l_run = 0.0f;

    const int sw = (q16 & 7) << 2;   // sV read swizzle (R12 verbatim)

    if (bmaxb >= s) {
        stage(0, s);
        int t1 = s + NSg; if (t1 > bmaxb) t1 = bmaxb;
        stage(1, t1);
        asm volatile("s_waitcnt vmcnt(9) lgkmcnt(0)" ::: "memory");  // buf0 + sMW ready
        __builtin_amdgcn_s_barrier();

        int cur = 0;
        for (int t = s; t <= bmaxb; t += NSg) {
            const int vb = t * 32;
            const unsigned mw = sMW[t];            // uniform LDS broadcast, no VMEM
            if (mw == 0u) break;                   // monotone length mask; uniform
            const bool act = waveActive && (t <= bound);
            const _Float16* sVc  = &sV[cur][0];
            const char*     sVTc = &sVT[cur][0];

            // === QK: S^T = V x Q^T (full K=512, 4 chains; dup across d-pair) ===
            f32x4 s0a = (f32x4){0.f,0.f,0.f,0.f}, s0b = s0a, s1a = s0a, s1b = s0a;
            if (act) {
                __builtin_amdgcn_s_setprio(1);
#pragma unroll
                for (int kc = 0; kc < 16; kc += 2) {
                    int c0 = ((kc * 4 + grp) ^ sw) << 4;
                    int c1 = (((kc + 1) * 4 + grp) ^ sw) << 4;
                    f16x8 a00 = *(const f16x8*)((const char*)sVc + q16 * 1024 + c0);
                    s0a = __builtin_amdgcn_mfma_f32_16x16x32_f16(a00, qreg[kc], s0a, 0, 0, 0);
                    f16x8 a10 = *(const f16x8*)((const char*)sVc + (16 + q16) * 1024 + c0);
                    s1a = __builtin_amdgcn_mfma_f32_16x16x32_f16(a10, qreg[kc], s1a, 0, 0, 0);
                    f16x8 a01 = *(const f16x8*)((const char*)sVc + q16 * 1024 + c1);
                    s0b = __builtin_amdgcn_mfma_f32_16x16x32_f16(a01, qreg[kc + 1], s0b, 0, 0, 0);
                    f16x8 a11 = *(const f16x8*)((const char*)sVc + (16 + q16) * 1024 + c1);
                    s1b = __builtin_amdgcn_mfma_f32_16x16x32_f16(a11, qreg[kc + 1], s1b, 0, 0, 0);
                }
                __builtin_amdgcn_s_setprio(0);

                f32x4 s0 = s0a + s0b, s1 = s1a + s1b;
                float p[8];
                float tm = -3.0e38f;
#pragma unroll
                for (int i = 0; i < 8; ++i) {
                    int vloc = ((i < 4) ? 0 : 16) + grp * 4 + (i & 3);
                    float x = (i < 4) ? s0[i] : s1[i - 4];
                    bool valid = ((vb + vloc) <= qrow) && ((mw >> vloc) & 1u);
                    x = valid ? x : (x - 1e9f);
                    p[i] = x;
                    tm = fmaxf(tm, x);
                }
                tm = fmaxf(tm, __shfl_xor(tm, 16, 64));
                tm = fmaxf(tm, __shfl_xor(tm, 32, 64));
                if (!__all(tm <= m_run + 8.0f)) {          // defer-max (T13)
                    float mn = fmaxf(m_run, tm);
                    float rr = __expf(m_run - mn);
                    l_run *= rr;
#pragma unroll
                    for (int c = 0; c < 16; ++c) acc[c] *= rr;
                    m_run = mn;
                }
                float ps = 0.0f;
#pragma unroll
                for (int i = 0; i < 8; ++i) { p[i] = __expf(p[i] - m_run); ps += p[i]; }
                ps += __shfl_xor(ps, 16, 64);
                ps += __shfl_xor(ps, 32, 64);
                l_run += ps;

                // P B-frag in-register (verified R8/R9/R12): shuffle both pairs, select at dest
                int pk0 = __builtin_bit_cast(int, __builtin_amdgcn_cvt_pkrtz(p[0], p[1]));
                int pk1 = __builtin_bit_cast(int, __builtin_amdgcn_cvt_pkrtz(p[2], p[3]));
                int pk2 = __builtin_bit_cast(int, __builtin_amdgcn_cvt_pkrtz(p[4], p[5]));
                int pk3 = __builtin_bit_cast(int, __builtin_amdgcn_cvt_pkrtz(p[6], p[7]));
                int lo = q16 + ((grp & 1) << 5);
                int hi = lo + 16;
                int a0 = __shfl(pk0, lo, 64);
                int a1 = __shfl(pk1, lo, 64);
                int a2 = __shfl(pk0, hi, 64);
                int a3 = __shfl(pk1, hi, 64);
                int c0s = __shfl(pk2, lo, 64);
                int c1s = __shfl(pk3, lo, 64);
                int c2s = __shfl(pk2, hi, 64);
                int c3s = __shfl(pk3, hi, 64);
                bool hb = (grp & 2) != 0;
                i32x4 f;
                f[0] = hb ? c0s : a0;
                f[1] = hb ? c1s : a1;
                f[2] = hb ? c2s : a2;
                f[3] = hb ? c3s : a3;
                f16x8 pf = __builtin_bit_cast(f16x8, f);

                // === PV: out^T[d][q16] += VT x P^T over this wave's 256-d half ===
                // 80B rows: chunk grp of row d at d*80 + grp*16; slot=(5d+grp)%8 even.
                __builtin_amdgcn_s_setprio(1);
#pragma unroll
                for (int c = 0; c < 16; ++c) {
                    int d = dhalf * 256 + c * 16 + q16;
                    f16x8 a = *(const f16x8*)(sVTc + d * 80 + (grp << 4));
                    acc[c] = __builtin_amdgcn_mfma_f32_16x16x32_f16(a, pf, acc[c], 0, 0, 0);
                }
                __builtin_amdgcn_s_setprio(0);
            }
            __builtin_amdgcn_s_barrier();              // B1: all waves done reading cur
            int t2 = t + 2 * NSg; if (t2 > bmaxb) t2 = bmaxb;
            stage(cur, t2);                            // overwrite freed buffer (+9)
            asm volatile("s_waitcnt vmcnt(9)" ::: "memory");  // nxt's loads (1 iter old) landed
            __builtin_amdgcn_s_barrier();              // B2: nxt ready block-wide
            cur ^= 1;
        }
    }
    asm volatile("s_waitcnt vmcnt(0) lgkmcnt(0)" ::: "memory");

    // ---- epilogue: normalized f16 partials + (m,l) ----
    float inv = (l_run > 0.f) ? (1.0f / l_run) : 0.0f;
    int rowInB = pairId * 16 + q16;
    _Float16* pb = pacc + (((size_t)(b * NSLOT + slot) * 64) + rowInB) * DIM;
#pragma unroll
    for (int c = 0; c < 16; ++c) {
        f16x4 hh;
#pragma unroll
        for (int j = 0; j < 4; ++j) hh[j] = (_Float16)(acc[c][j] * inv);
        *(f16x4*)(pb + dhalf * 256 + c * 16 + grp * 4) = hh;
    }
    if (dhalf == 0 && grp == 0) {
        size_t mi = (((size_t)(b * NSLOT + slot) * 64) + rowInB) * 2;
        pml[mi]     = m_run;
        pml[mi + 1] = l_run;
    }
}

__global__ __launch_bounds__(256)
void combine_kernel(const _Float16* __restrict__ pacc, const float* __restrict__ pml,
                    const void* __restrict__ qmask, float* __restrict__ out) {
    int gid = blockIdx.x * 256 + threadIdx.x;
    int row = gid >> 7;
    int c   = (gid & 127) * 4;
    if (row >= NROW) return;
    int b      = row >> 11;
    int local  = row & 2047;
    int g      = local >> 6;          // 64 rows per group
    int rowInG = local & 63;
    int ns     = sched_ns(g);
    int st     = sched_start(g);

    float m = -3.0e38f;
    for (int s2 = 0; s2 < ns; ++s2) {
        size_t idx = ((size_t)(b * NSLOT + st + s2) * 64) + rowInG;
        float l2 = pml[idx * 2 + 1];
        if (l2 > 0.f) m = fmaxf(m, pml[idx * 2]);
    }
    float L = 0.f;
    f32x4 o = (f32x4){0.f, 0.f, 0.f, 0.f};
    for (int s2 = 0; s2 < ns; ++s2) {
        size_t idx = ((size_t)(b * NSLOT + st + s2) * 64) + rowInG;
        float l2 = pml[idx * 2 + 1];
        if (l2 > 0.f) {
            float wgt = __expf(pml[idx * 2] - m) * l2;
            L += wgt;
            f16x4 hh = *(const f16x4*)(pacc + idx * DIM + c);
#pragma unroll
            for (int j = 0; j < 4; ++j) o[j] += wgt * (float)hh[j];
        }
    }
    int fmt = mask_fmt(qmask);
    bool qb = mask_bit(qmask, fmt, (size_t)row);
    float invL = (L > 0.f && qb) ? (1.0f / L) : 0.f;
    o *= invL;
    *(f32x4*)(out + (size_t)row * DIM + c) = o;
}

extern "C" void kernel_launch(void* const* d_in, const int* in_sizes, int n_in,
                              void* d_out, int out_size, void* d_ws, size_t ws_size,
                              hipStream_t stream) {
    const float* q = (const float*)d_in[0];
    const float* v = (const float*)d_in[1];
    const void* qm = d_in[2];
    const void* vm = d_in[3];
    float* out = (float*)d_out;

    const size_t nElem = (size_t)NB * TQ * DIM;                    // 8,388,608
    const size_t wqB   = nElem * sizeof(_Float16);                 // 16.78 MB
    const size_t wvB   = wqB, wvtB = wqB;
    const size_t paccB = (size_t)NB * NSLOT * 64 * DIM * sizeof(_Float16);  // 33.0 MB
    const size_t pmlB  = (size_t)NB * NSLOT * 64 * 2 * sizeof(float);       // 0.26 MB

    if (ws_size < wqB + wvB + wvtB + paccB + pmlB) {   // ~84 MB; proven available
        (void)hipMemsetAsync(d_out, 0, (size_t)out_size * sizeof(float), stream);
        return;
    }
    _Float16* wq   = (_Float16*)d_ws;
    _Float16* wv   = (_Float16*)((char*)d_ws + wqB);
    _Float16* wvt  = (_Float16*)((char*)d_ws + wqB + wvB);
    _Float16* pacc = (_Float16*)((char*)d_ws + wqB + wvB + wvtB);
    float*    pml  = (float*)((char*)d_ws + wqB + wvB + wvtB + paccB);

    int n8 = (int)(nElem / 8);
    cvt_f16_kernel<<<dim3(n8 / 256), dim3(256), 0, stream>>>(q, wq, n8);
    prep_v_kernel<<<dim3(2048), dim3(256), 0, stream>>>(v, wv, wvt);
    attn_kernel<<<dim3(NB * NSLOT), dim3(512), 0, stream>>>(wq, wv, wvt, qm, vm, pacc, pml);
    combine_kernel<<<dim3(NROW * 128 / 256), dim3(256), 0, stream>>>(pacc, pml, qm, out);
}